// Round 6
// baseline (1146.815 us; speedup 1.0000x reference)
//
#include <hip/hip_runtime.h>
#include <math.h>

#define T_TOK 2048
#define HID   4096
#define NH    32
#define NKV   8
#define HD    128
#define QKVD  6144   // (NH + 2*NKV) * HD
#define V_OFF 5120   // NH*HD + NKV*HD

typedef __attribute__((ext_vector_type(8))) short short8;
typedef __attribute__((ext_vector_type(4))) short s4v;
typedef __attribute__((ext_vector_type(4))) float f32x4;

__device__ __forceinline__ unsigned short f2bf(float x) {
  unsigned u = __builtin_bit_cast(unsigned, x);
  u += 0x7fffu + ((u >> 16) & 1u);          // round-nearest-even
  return (unsigned short)(u >> 16);
}
__device__ __forceinline__ float bf2f(unsigned short h) {
  unsigned u = ((unsigned)h) << 16;
  return __builtin_bit_cast(float, u);
}

// global -> LDS direct DMA, 16 B per lane
__device__ __forceinline__ void g2lds16(const void* g, void* l) {
  __builtin_amdgcn_global_load_lds(
      (const __attribute__((address_space(1))) unsigned int*)g,
      (__attribute__((address_space(3))) unsigned int*)(unsigned int)(unsigned long long)l,
      16, 0, 0);
}

// ---------------- wave helpers (wave64) ----------------
__device__ __forceinline__ float wave_sum(float v) {
  for (int off = 32; off; off >>= 1) v += __shfl_xor(v, off, 64);
  return v;
}
__device__ __forceinline__ float wave_max(float v) {
  for (int off = 32; off; off >>= 1) v = fmaxf(v, __shfl_xor(v, off, 64));
  return v;
}
__device__ __forceinline__ float wave_min(float v) {
  for (int off = 32; off; off >>= 1) v = fminf(v, __shfl_xor(v, off, 64));
  return v;
}

// ---------------- f32 -> bf16 weight conversion (memory-bound) ----------------
__global__ __launch_bounds__(256) void k_f32_to_bf16(
    const float* __restrict__ s, unsigned short* __restrict__ d, int n8)
{
  int i = blockIdx.x * 256 + threadIdx.x;
  if (i >= n8) return;
  const float4* sp = (const float4*)s + (size_t)i * 2;
  float4 a = sp[0], b = sp[1];
  short8 o;
  o[0] = f2bf(a.x); o[1] = f2bf(a.y); o[2] = f2bf(a.z); o[3] = f2bf(a.w);
  o[4] = f2bf(b.x); o[5] = f2bf(b.y); o[6] = f2bf(b.z); o[7] = f2bf(b.w);
  *(short8*)(d + (size_t)i * 8) = o;
}

// ---------------- K1: bilinear (lnL^T X lnR) + 8-bit sym fake-quant ----------------
// outputs INTEGER q as bf16 (exact, |q|<=128) + per-token f32 scale
__global__ __launch_bounds__(256) void k_bilinear_quant(
    const float* __restrict__ hidden, const float* __restrict__ lnL,
    const float* __restrict__ lnR, unsigned short* __restrict__ xqb,
    float* __restrict__ scales)
{
  __shared__ float sX[4096];
  __shared__ float sT[4096];
  __shared__ float sL[4096];
  __shared__ float sR[4096];
  __shared__ float sm[4];
  const int t = blockIdx.x;
  const int tid = threadIdx.x;
  const float* src = hidden + (size_t)t * 4096;
  for (int i = tid; i < 4096; i += 256) { sX[i] = src[i]; sL[i] = lnL[i]; sR[i] = lnR[i]; }
  __syncthreads();
  #pragma unroll
  for (int u = 0; u < 16; u++) {
    int p = tid + 256 * u;
    int l = p >> 6, R = p & 63;
    float a = 0.f;
    #pragma unroll 8
    for (int r = 0; r < 64; r++) a += sX[(l << 6) + r] * sR[(r << 6) + R];
    sT[p] = a;
  }
  __syncthreads();
  float vals[16];
  float amax = 0.f;
  #pragma unroll
  for (int u = 0; u < 16; u++) {
    int p = tid + 256 * u;
    int L = p >> 6, R = p & 63;
    float a = 0.f;
    #pragma unroll 8
    for (int l = 0; l < 64; l++) a += sL[(l << 6) + L] * sT[(l << 6) + R];
    vals[u] = a;
    amax = fmaxf(amax, fabsf(a));
  }
  amax = wave_max(amax);
  if ((tid & 63) == 0) sm[tid >> 6] = amax;
  __syncthreads();
  amax = fmaxf(fmaxf(sm[0], sm[1]), fmaxf(sm[2], sm[3]));
  float scale = fmaxf(amax * (1.0f / 127.0f), 1e-8f);
  if (tid == 0) scales[t] = scale;
  #pragma unroll
  for (int u = 0; u < 16; u++) {
    int p = tid + 256 * u;
    float q = rintf(vals[u] / scale);
    q = fminf(fmaxf(q, -128.f), 127.f);
    xqb[(size_t)t * 4096 + p] = f2bf(q);   // exact integer in bf16
  }
}

// ---------------- split-precision MFMA GEMM (QKV): C = scale[m] * A @ Bf^T ----------------
__global__ __launch_bounds__(256) void k_gemm_split(
    const unsigned short* __restrict__ A, const float* __restrict__ Bf,
    const float* __restrict__ scales, float* __restrict__ C, int N, int K)
{
  __shared__ __align__(16) unsigned short sA[128 * 32];
  __shared__ __align__(16) unsigned short sBh[128 * 32];
  __shared__ __align__(16) unsigned short sBl[128 * 32];
  __shared__ float sS[128];
  const int tid = threadIdx.x;
  const int w = tid >> 6, lane = tid & 63;
  const int n16 = lane & 15, quad = lane >> 4;
  const int bm = blockIdx.y << 7, bn = blockIdx.x << 7;
  const int wm = (w >> 1) << 6, wn = (w & 1) << 6;
  if (tid < 128) sS[tid] = scales[bm + tid];
  const int srow = lane >> 2;
  const int scol = (lane & 3) << 3;
  f32x4 acc[4][4];
  #pragma unroll
  for (int i = 0; i < 4; i++)
    #pragma unroll
    for (int j = 0; j < 4; j++) acc[i][j] = (f32x4){0.f, 0.f, 0.f, 0.f};

  for (int k0 = 0; k0 < K; k0 += 32) {
    __syncthreads();
    #pragma unroll
    for (int r = 0; r < 2; r++) {
      const int grp = (r << 2) + w;
      const int row = (grp << 4) + srow;
      g2lds16(A + (size_t)(bm + row) * K + k0 + scol, &sA[(grp << 9) + lane * 8]);
    }
    #pragma unroll
    for (int it = 0; it < 4; it++) {
      int idx = it * 256 + tid;
      int row = idx >> 3, c4 = (idx & 7) << 2;
      float4 f = *(const float4*)(Bf + (size_t)(bn + row) * K + k0 + c4);
      unsigned short h0 = f2bf(f.x), h1 = f2bf(f.y), h2 = f2bf(f.z), h3 = f2bf(f.w);
      *(s4v*)&sBh[row * 32 + c4] = (s4v){(short)h0, (short)h1, (short)h2, (short)h3};
      *(s4v*)&sBl[row * 32 + c4] = (s4v){
          (short)f2bf(f.x - bf2f(h0)), (short)f2bf(f.y - bf2f(h1)),
          (short)f2bf(f.z - bf2f(h2)), (short)f2bf(f.w - bf2f(h3))};
    }
    __syncthreads();
    short8 af[4], bh[4], bl[4];
    #pragma unroll
    for (int t = 0; t < 4; t++) {
      af[t] = *(const short8*)&sA [(wm + (t << 4) + n16) * 32 + (quad << 3)];
      bh[t] = *(const short8*)&sBh[(wn + (t << 4) + n16) * 32 + (quad << 3)];
      bl[t] = *(const short8*)&sBl[(wn + (t << 4) + n16) * 32 + (quad << 3)];
    }
    #pragma unroll
    for (int i = 0; i < 4; i++)
      #pragma unroll
      for (int j = 0; j < 4; j++) {
        acc[i][j] = __builtin_amdgcn_mfma_f32_16x16x32_bf16(af[i], bh[j], acc[i][j], 0, 0, 0);
        acc[i][j] = __builtin_amdgcn_mfma_f32_16x16x32_bf16(af[i], bl[j], acc[i][j], 0, 0, 0);
      }
  }

  #pragma unroll
  for (int i = 0; i < 4; i++) {
    #pragma unroll
    for (int r = 0; r < 4; r++) {
      int lrow = wm + (i << 4) + (quad << 2) + r;
      float s = sS[lrow];
      float* crow = C + (size_t)(bm + lrow) * N + bn + wn;
      #pragma unroll
      for (int j = 0; j < 4; j++)
        crow[(j << 4) + n16] = acc[i][j][r] * s;
    }
  }
}

// ---------------- MFMA GEMM (out-proj): C[m][n] = scale[m] * sum_k A[m][k]*B[n][k] ----------------
__global__ __launch_bounds__(256) void k_gemm_mfma(
    const unsigned short* __restrict__ A, const unsigned short* __restrict__ Bm,
    const float* __restrict__ scales, float* __restrict__ C, int N, int K)
{
  __shared__ __align__(16) unsigned short sA[128 * 32];
  __shared__ __align__(16) unsigned short sB[128 * 32];
  __shared__ float sS[128];
  const int tid = threadIdx.x;
  const int w = tid >> 6, lane = tid & 63;
  const int n16 = lane & 15, quad = lane >> 4;
  const int bm = blockIdx.y << 7, bn = blockIdx.x << 7;
  const int wm = (w >> 1) << 6, wn = (w & 1) << 6;
  if (tid < 128) sS[tid] = scales[bm + tid];
  const int srow = lane >> 2;
  const int scol = (lane & 3) << 3;
  f32x4 acc[4][4];
  #pragma unroll
  for (int i = 0; i < 4; i++)
    #pragma unroll
    for (int j = 0; j < 4; j++) acc[i][j] = (f32x4){0.f, 0.f, 0.f, 0.f};

  for (int k0 = 0; k0 < K; k0 += 32) {
    __syncthreads();
    #pragma unroll
    for (int r = 0; r < 2; r++) {
      const int grp = (r << 2) + w;
      const int row = (grp << 4) + srow;
      g2lds16(A  + (size_t)(bm + row) * K + k0 + scol, &sA[(grp << 9) + lane * 8]);
      g2lds16(Bm + (size_t)(bn + row) * K + k0 + scol, &sB[(grp << 9) + lane * 8]);
    }
    __syncthreads();
    short8 af[4], bfr[4];
    #pragma unroll
    for (int t = 0; t < 4; t++) {
      af[t]  = *(const short8*)&sA[(wm + (t << 4) + n16) * 32 + (quad << 3)];
      bfr[t] = *(const short8*)&sB[(wn + (t << 4) + n16) * 32 + (quad << 3)];
    }
    #pragma unroll
    for (int i = 0; i < 4; i++)
      #pragma unroll
      for (int j = 0; j < 4; j++)
        acc[i][j] = __builtin_amdgcn_mfma_f32_16x16x32_bf16(af[i], bfr[j], acc[i][j], 0, 0, 0);
  }

  #pragma unroll
  for (int i = 0; i < 4; i++) {
    #pragma unroll
    for (int r = 0; r < 4; r++) {
      int lrow = wm + (i << 4) + (quad << 2) + r;
      float s = sS[lrow];
      float* crow = C + (size_t)(bm + lrow) * N + bn + wn;
      #pragma unroll
      for (int j = 0; j < 4; j++)
        crow[(j << 4) + n16] = acc[i][j][r] * s;
    }
  }
}

// ---------------- Q/K processing: rmsnorm -> rope -> @k_trans (-> 4-bit asym quant for K) ----------------
__global__ __launch_bounds__(64) void k_qkproc(
    const float* __restrict__ qkv, const int* __restrict__ pos,
    const float* __restrict__ nw, const float* __restrict__ kt,
    unsigned short* __restrict__ dst_, int nheads, int off_n, int do_quant)
{
  const int h = blockIdx.x, t = blockIdx.y;
  const int lane = threadIdx.x;
  const float* src = qkv + (size_t)t * QKVD + off_n + h * HD;
  float x1 = src[lane], x2 = src[lane + 64];
  float ss = wave_sum(x1 * x1 + x2 * x2);
  float rinv = 1.0f / sqrtf(ss * (1.0f / 128.0f) + 1e-6f);
  x1 *= rinv * nw[lane];
  x2 *= rinv * nw[lane + 64];
  const float p = (float)pos[t];
  const float invf = exp2f((float)lane * (-19.931568569324174f / 64.0f)); // theta^{-j/64}
  const float fr = p * invf;
  const float c = cosf(fr), s = sinf(fr);
  const float y1 = x1 * c - x2 * s;
  const float y2 = x2 * c + x1 * s;
  __shared__ float sq[128];
  sq[lane] = y1; sq[lane + 64] = y2;
  __syncthreads();
  float o1 = 0.f, o2 = 0.f;
  #pragma unroll 8
  for (int e = 0; e < 128; e++) {
    float qe = sq[e];
    o1 += qe * kt[(e << 7) + lane];
    o2 += qe * kt[(e << 7) + 64 + lane];
  }
  if (do_quant) {
    float mn = fminf(wave_min(fminf(o1, o2)), 0.f);
    float mx = fmaxf(wave_max(fmaxf(o1, o2)), 0.f);
    float scale = fmaxf((mx - mn) * (1.0f / 15.0f), 1e-8f);
    float zero = rintf(-mn / scale);
    float q1 = fminf(fmaxf(rintf(o1 / scale) + zero, 0.f), 15.f);
    float q2 = fminf(fmaxf(rintf(o2 / scale) + zero, 0.f), 15.f);
    o1 = (q1 - zero) * scale;
    o2 = (q2 - zero) * scale;
  }
  unsigned short* d = dst_ + ((size_t)t * nheads + h) * HD;
  d[lane] = f2bf(o1); d[lane + 64] = f2bf(o2);
}

// ---------------- V: 4-bit group-asym quant, output TRANSPOSED bf16 [kvh][d][t] ----------------
__global__ __launch_bounds__(256) void k_vproc(
    const float* __restrict__ qkv, unsigned short* __restrict__ vpT)
{
  __shared__ __align__(16) unsigned short sTt[128][72];
  const int kvh = blockIdx.x;
  const int t0  = blockIdx.y * 64;
  const int tid = threadIdx.x;
  const int tl = tid >> 2, part = tid & 3;
  const float* src = qkv + (size_t)(t0 + tl) * QKVD + V_OFF + kvh * HD + part * 32;
  float v[32];
  float mn = 0.f, mx = 0.f;
  #pragma unroll
  for (int c = 0; c < 8; c++) {
    float4 f = *(const float4*)(src + c * 4);
    v[c*4+0] = f.x; v[c*4+1] = f.y; v[c*4+2] = f.z; v[c*4+3] = f.w;
    mn = fminf(mn, fminf(fminf(f.x, f.y), fminf(f.z, f.w)));
    mx = fmaxf(mx, fmaxf(fmaxf(f.x, f.y), fmaxf(f.z, f.w)));
  }
  mn = fminf(mn, __shfl_xor(mn, 1, 64)); mn = fminf(mn, __shfl_xor(mn, 2, 64));
  mx = fmaxf(mx, __shfl_xor(mx, 1, 64)); mx = fmaxf(mx, __shfl_xor(mx, 2, 64));
  float scale = fmaxf((mx - mn) * (1.0f / 15.0f), 1e-8f);
  float zero  = rintf(-mn / scale);
  #pragma unroll
  for (int j = 0; j < 32; j++) {
    float q = fminf(fmaxf(rintf(v[j] / scale) + zero, 0.f), 15.f);
    sTt[part * 32 + j][tl] = f2bf((q - zero) * scale);
  }
  __syncthreads();
  for (int i = tid; i < 128 * 8; i += 256) {
    int d = i >> 3, seg = i & 7;
    *(float4*)(vpT + ((size_t)kvh * HD + d) * T_TOK + t0 + seg * 8) =
        *(const float4*)&sTt[d][seg * 8];
  }
}

// ---------------- paired MFMA flash attention, causal, GQA rep=4 ----------------
// block = (head h, q-tile pair {pi, 31-pi}): work = (pi+1)+(32-pi) = 33 tiles, uniform.
// K/V staging shared by both q-tiles; B-frags read once per tile, used for both.
__global__ __launch_bounds__(256) void k_attn_pair(
    const unsigned short* __restrict__ qp, const unsigned short* __restrict__ kp,
    const unsigned short* __restrict__ vpT, float* __restrict__ ao)
{
  __shared__ __align__(16) unsigned short sK[64][136];
  __shared__ __align__(16) unsigned short sVt[128][72];
  __shared__ __align__(16) unsigned short sP[4][2][16][72];
  const int pi = blockIdx.x, h = blockIdx.y;
  const int kvh = h >> 2;
  const int tlo = pi, thi = 31 - pi;
  const int tid = threadIdx.x;
  const int w = tid >> 6, lane = tid & 63;
  const int n = lane & 15, quad = lane >> 4;
  const int q0t[2] = { tlo * 64, thi * 64 };

  short8 qfrag[2][4];
  #pragma unroll
  for (int tt = 0; tt < 2; tt++) {
    const unsigned short* qrow = qp + ((size_t)(q0t[tt] + w * 16 + n) * NH + h) * HD;
    #pragma unroll
    for (int kk = 0; kk < 4; kk++)
      qfrag[tt][kk] = *(const short8*)(qrow + kk * 32 + quad * 8);
  }

  f32x4 oacc[2][8];
  float m_i[2][4], l_i[2][4];
  #pragma unroll
  for (int tt = 0; tt < 2; tt++) {
    #pragma unroll
    for (int dt = 0; dt < 8; dt++) oacc[tt][dt] = (f32x4){0.f, 0.f, 0.f, 0.f};
    #pragma unroll
    for (int r = 0; r < 4; r++) { m_i[tt][r] = -1e30f; l_i[tt][r] = 0.f; }
  }

  const float sm_scale = 0.08838834764831845f;  // 128^-0.5
  const float LOG2E = 1.4426950408889634f;

  for (int st = 0; st <= thi; st++) {
    const int s0 = st * 64;
    __syncthreads();
    for (int i = tid; i < 1024; i += 256) {            // K tile 64x128
      int row = i >> 4, ch = i & 15;
      *(float4*)&sK[row][ch * 8] =
          *(const float4*)(kp + ((size_t)(s0 + row) * NKV + kvh) * HD + ch * 8);
    }
    for (int i = tid; i < 1024; i += 256) {            // V^T tile 128x64
      int row = i >> 3, ch = i & 7;
      *(float4*)&sVt[row][ch * 8] =
          *(const float4*)(vpT + ((size_t)kvh * HD + row) * T_TOK + s0 + ch * 8);
    }
    __syncthreads();

    const int act0 = (st <= tlo) ? 0 : 1;   // active tiles: [act0, 1]

    // S = Q K^T — B-frags shared across both q-tiles
    f32x4 sacc[2][4];
    #pragma unroll
    for (int tt = 0; tt < 2; tt++)
      #pragma unroll
      for (int jt = 0; jt < 4; jt++) sacc[tt][jt] = (f32x4){0.f, 0.f, 0.f, 0.f};
    #pragma unroll
    for (int jt = 0; jt < 4; jt++) {
      short8 bk[4];
      #pragma unroll
      for (int kk = 0; kk < 4; kk++)
        bk[kk] = *(const short8*)&sK[jt * 16 + n][kk * 32 + quad * 8];
      #pragma unroll
      for (int tt = 0; tt < 2; tt++) {
        if (tt < act0) continue;
        #pragma unroll
        for (int kk = 0; kk < 4; kk++)
          sacc[tt][jt] = __builtin_amdgcn_mfma_f32_16x16x32_bf16(qfrag[tt][kk], bk[kk], sacc[tt][jt], 0, 0, 0);
      }
    }

    // online softmax per active tile (mask only on diagonal tile)
    #pragma unroll
    for (int tt = 0; tt < 2; tt++) {
      if (tt < act0) continue;
      const bool diag = (st == (tt ? thi : tlo));
      float mx[4] = {-1e30f, -1e30f, -1e30f, -1e30f};
      #pragma unroll
      for (int jt = 0; jt < 4; jt++) {
        #pragma unroll
        for (int r = 0; r < 4; r++) {
          float v = sacc[tt][jt][r] * sm_scale;
          if (diag) {
            int sg = s0 + jt * 16 + n;
            int ig = q0t[tt] + w * 16 + quad * 4 + r;
            if (sg > ig) v = -1e30f;
          }
          sacc[tt][jt][r] = v;
          mx[r] = fmaxf(mx[r], v);
        }
      }
      #pragma unroll
      for (int off = 1; off < 16; off <<= 1)
        #pragma unroll
        for (int r = 0; r < 4; r++) mx[r] = fmaxf(mx[r], __shfl_xor(mx[r], off, 64));
      float alpha[4], psum[4];
      #pragma unroll
      for (int r = 0; r < 4; r++) {
        float m_new = fmaxf(m_i[tt][r], mx[r]);
        alpha[r] = exp2f((m_i[tt][r] - m_new) * LOG2E);
        m_i[tt][r] = m_new;
        psum[r] = 0.f;
      }
      #pragma unroll
      for (int jt = 0; jt < 4; jt++) {
        #pragma unroll
        for (int r = 0; r < 4; r++) {
          float pv = exp2f((sacc[tt][jt][r] - m_i[tt][r]) * LOG2E);
          psum[r] += pv;
          sP[w][tt][quad * 4 + r][jt * 16 + n] = f2bf(pv);
        }
      }
      #pragma unroll
      for (int off = 1; off < 16; off <<= 1)
        #pragma unroll
        for (int r = 0; r < 4; r++) psum[r] += __shfl_xor(psum[r], off, 64);
      #pragma unroll
      for (int r = 0; r < 4; r++) l_i[tt][r] = l_i[tt][r] * alpha[r] + psum[r];
      #pragma unroll
      for (int dt = 0; dt < 8; dt++)
        #pragma unroll
        for (int r = 0; r < 4; r++) oacc[tt][dt][r] *= alpha[r];
    }

    // O += P V — sP is wave-private (in-wave LDS ordering; no barrier needed),
    // V^T B-frags read once, used for both q-tiles
    short8 pf[2][2];
    #pragma unroll
    for (int tt = 0; tt < 2; tt++) {
      if (tt < act0) continue;
      #pragma unroll
      for (int kk = 0; kk < 2; kk++)
        pf[tt][kk] = *(const short8*)&sP[w][tt][n][kk * 32 + quad * 8];
    }
    #pragma unroll
    for (int dt = 0; dt < 8; dt++) {
      short8 bv[2];
      #pragma unroll
      for (int kk = 0; kk < 2; kk++)
        bv[kk] = *(const short8*)&sVt[dt * 16 + n][kk * 32 + quad * 8];
      #pragma unroll
      for (int tt = 0; tt < 2; tt++) {
        if (tt < act0) continue;
        #pragma unroll
        for (int kk = 0; kk < 2; kk++)
          oacc[tt][dt] = __builtin_amdgcn_mfma_f32_16x16x32_bf16(pf[tt][kk], bv[kk], oacc[tt][dt], 0, 0, 0);
      }
    }
  }

  #pragma unroll
  for (int tt = 0; tt < 2; tt++) {
    #pragma unroll
    for (int r = 0; r < 4; r++) {
      float linv = 1.0f / l_i[tt][r];
      int t = q0t[tt] + w * 16 + quad * 4 + r;
      float* dst = ao + (size_t)t * (NH * HD) + h * HD;
      #pragma unroll
      for (int dt = 0; dt < 8; dt++)
        dst[dt * 16 + n] = oacc[tt][dt][r] * linv;
    }
  }
}

// ---------------- head mix + 8-bit sym fake-quant: INTEGER bf16 out + scale ----------------
__global__ __launch_bounds__(256) void k_mix_quant(
    const float* __restrict__ ao, const float* __restrict__ ot,
    unsigned short* __restrict__ qob, float* __restrict__ scales)
{
  __shared__ float sA[4096];
  __shared__ float sO[1024];
  __shared__ float sm[4];
  const int t = blockIdx.x;
  const int tid = threadIdx.x;
  for (int i = tid; i < 4096; i += 256) sA[i] = ao[(size_t)t * 4096 + i];
  for (int i = tid; i < 1024; i += 256) sO[i] = ot[i];
  __syncthreads();
  float vals[16];
  float amax = 0.f;
  #pragma unroll
  for (int u = 0; u < 16; u++) {
    int o = tid + 256 * u;
    int ih = o >> 7, d = o & 127;
    float a = 0.f;
    #pragma unroll 8
    for (int j = 0; j < 32; j++) a += sO[j * 32 + ih] * sA[j * 128 + d];
    vals[u] = a;
    amax = fmaxf(amax, fabsf(a));
  }
  amax = wave_max(amax);
  if ((tid & 63) == 0) sm[tid >> 6] = amax;
  __syncthreads();
  amax = fmaxf(fmaxf(sm[0], sm[1]), fmaxf(sm[2], sm[3]));
  float scale = fmaxf(amax * (1.0f / 127.0f), 1e-8f);
  if (tid == 0) scales[t] = scale;
  #pragma unroll
  for (int u = 0; u < 16; u++) {
    int o = tid + 256 * u;
    float q = rintf(vals[u] / scale);
    q = fminf(fmaxf(q, -128.f), 127.f);
    qob[(size_t)t * 4096 + o] = f2bf(q);
  }
}

extern "C" void kernel_launch(void* const* d_in, const int* in_sizes, int n_in,
                              void* d_out, int out_size, void* d_ws, size_t ws_size,
                              hipStream_t stream) {
  const float* hidden    = (const float*)d_in[0];
  const int*   positions = (const int*)  d_in[1];
  const float* w_qkv     = (const float*)d_in[2];
  const float* w_o       = (const float*)d_in[3];
  const float* q_norm_w  = (const float*)d_in[4];
  const float* k_norm_w  = (const float*)d_in[5];
  const float* ln_left   = (const float*)d_in[6];
  const float* ln_right  = (const float*)d_in[7];
  const float* o_trans   = (const float*)d_in[8];
  const float* k_trans   = (const float*)d_in[9];
  float* out = (float*)d_out;
  char* ws = (char*)d_ws;

  // workspace layout, peak 120 MiB:
  float*          qkv  = (float*)(ws);                       // 48 MiB f32 (T x 6144); reused as ao (32 MiB)
  unsigned short* xqb  = (unsigned short*)(ws + 50331648);   // 16 MiB bf16 int A1; reused as qob (A2)
  float*          sc1  = (float*)(ws + 67108864);            // 8 KiB
  float*          sc2  = (float*)(ws + 67117056);            // 8 KiB
  unsigned short* qp   = (unsigned short*)(ws + 67125248);   // 16 MiB bf16 (T x 32 x 128)
  unsigned short* kp   = (unsigned short*)(ws + 83902464);   //  4 MiB bf16 (T x 8 x 128)
  unsigned short* vpT  = (unsigned short*)(ws + 88096768);   //  4 MiB bf16 (8 x 128 x T)
  unsigned short* wob  = (unsigned short*)(ws + 92291072);   // 32 MiB bf16 w_o
  float*          ao   = qkv;
  unsigned short* qob  = xqb;

  k_bilinear_quant<<<T_TOK, 256, 0, stream>>>(hidden, ln_left, ln_right, xqb, sc1);
  k_gemm_split<<<dim3(QKVD / 128, T_TOK / 128), 256, 0, stream>>>(xqb, w_qkv, sc1, qkv, QKVD, HID);
  k_qkproc<<<dim3(NH, T_TOK), 64, 0, stream>>>(qkv, positions, q_norm_w, k_trans, qp, NH, 0, 0);
  k_qkproc<<<dim3(NKV, T_TOK), 64, 0, stream>>>(qkv, positions, k_norm_w, k_trans, kp, NKV, NH * HD, 1);
  k_vproc<<<dim3(NKV, T_TOK / 64), 256, 0, stream>>>(qkv, vpT);
  k_f32_to_bf16<<<(HID * HID / 8 + 255) / 256, 256, 0, stream>>>(w_o, wob, HID * HID / 8);
  k_attn_pair<<<dim3(16, NH), 256, 0, stream>>>(qp, kp, vpT, ao);            // qkv dead now
  k_mix_quant<<<T_TOK, 256, 0, stream>>>(ao, o_trans, qob, sc2);             // xqb dead now
  k_gemm_mfma<<<dim3(HID / 128, T_TOK / 128), 256, 0, stream>>>(qob, wob, sc2, out, HID, HID);
}